// Round 11
// baseline (227.902 us; speedup 1.0000x reference)
//
#include <hip/hip_runtime.h>

#define IMG_H 512
#define IMG_W 512
#define NCLS  21
#define HWC   (IMG_H * IMG_W)   // 262144 = 2^18

// 1/ln(501)
#define INV_LOG_MAXR 0.16085936f

// CE staging geometry
#define CE_BLK 128                 // threads/block (2 waves)
#define CE_PX  (CE_BLK * 4)        // 512 pixels per block
#define CE_LDS_FLOATS (NCLS * CE_PX)   // 10752 floats = 43008 B -> 3 blocks/CU

typedef const __attribute__((address_space(1))) void* gptr_t;
typedef __attribute__((address_space(3))) void*       lptr_t;

// ---------------- union-find ----------------
// Lock-free union-find, union-by-min + path halving (ECL-CC style).
// Plain loads are safe: any published parent value is a true ancestor
// (parents only decrease), CAS return values drive progress in unite(),
// and kernel boundaries make all CAS results visible to plain loads.

__device__ __forceinline__ int find_root(int* parent, int x) {
    int p = parent[x];
    while (p != x) {
        int gp = parent[p];
        if (gp != p) parent[x] = gp;   // path halving: gp is an ancestor
        x = gp;
        p = parent[x];
    }
    return x;
}

__device__ __forceinline__ void unite(int* parent, int a, int b) {
    while (true) {
        a = find_root(parent, a);
        b = find_root(parent, b);
        if (a == b) return;
        if (a < b) {
            int old = atomicCAS(&parent[b], b, a);
            if (old == b) return;
            b = old;   // coherent value from CAS -> guaranteed progress
        } else {
            int old = atomicCAS(&parent[a], a, b);
            if (old == a) return;
            a = old;
        }
    }
}

// ---------------- bookkeeping kernels (unchanged from R8/R10) ----------------

__global__ __launch_bounds__(256) void init_kernel(int* __restrict__ parent,
                                                   int* __restrict__ counts,
                                                   float* __restrict__ acc,
                                                   int* __restrict__ done,
                                                   int n) {
    int idx = blockIdx.x * blockDim.x + threadIdx.x;
    int i4 = idx * 4;
    if (i4 < n) {
        *reinterpret_cast<int4*>(parent + i4) = make_int4(i4, i4 + 1, i4 + 2, i4 + 3);
        *reinterpret_cast<int4*>(counts + i4) = make_int4(0, 0, 0, 0);
    }
    if (idx == 0) { *acc = 0.0f; *done = 0; }
}

__global__ __launch_bounds__(256) void merge_kernel(const int* __restrict__ tgt,
                                                    int* __restrict__ parent,
                                                    int n) {
    int i4 = (blockIdx.x * blockDim.x + threadIdx.x) * 4;
    if (i4 >= n) return;
    int4 tv = *reinterpret_cast<const int4*>(tgt + i4);
    int tj[4] = {tv.x, tv.y, tv.z, tv.w};

#pragma unroll
    for (int j = 0; j < 3; ++j)
        if (tj[j] > 0 && tj[j + 1] == tj[j]) unite(parent, i4 + j, i4 + j + 1);

    int w3 = (i4 + 3) & (IMG_W - 1);
    if (tj[3] > 0 && w3 + 1 < IMG_W) {
        if (tgt[i4 + 4] == tj[3]) unite(parent, i4 + 3, i4 + 4);
    }

    int h = (i4 >> 9) & (IMG_H - 1);
    if (h + 1 < IMG_H) {
        int4 dv = *reinterpret_cast<const int4*>(tgt + i4 + IMG_W);
        int dj[4] = {dv.x, dv.y, dv.z, dv.w};
#pragma unroll
        for (int j = 0; j < 4; ++j)
            if (tj[j] > 0 && dj[j] == tj[j]) unite(parent, i4 + j, i4 + j + IMG_W);
    }
}

__global__ __launch_bounds__(256) void count_kernel(const int* __restrict__ tgt,
                                                    int* __restrict__ parent,
                                                    int* __restrict__ counts,
                                                    int n) {
    int i4 = (blockIdx.x * blockDim.x + threadIdx.x) * 4;
    if (i4 >= n) return;
    int4 tv = *reinterpret_cast<const int4*>(tgt + i4);
    int tj[4] = {tv.x, tv.y, tv.z, tv.w};
#pragma unroll
    for (int j = 0; j < 4; ++j) {
        if (tj[j] > 0) {
            int r = find_root(parent, i4 + j);
            parent[i4 + j] = r;          // full compression: CE reads root directly
            atomicAdd(&counts[r], 1);
        }
    }
}

// ---------------- CE kernel: global_load_lds staged ----------------
// The DMA-to-LDS path has no destination VGPR, so all 21 class loads per
// wave stay outstanding regardless of register allocation (the R3/R5/R10
// data showed the compiler serializes register loads at ~400cy each).
// 128 thr x 4 px = 512 px/block; LDS [c][px] = 43008 B -> 3 blocks/CU;
// 3 blk x 2 waves x 21 loads x 1KB = 126 KB in flight per CU.

__global__ __launch_bounds__(CE_BLK) void ce_weight_kernel(
        const float* __restrict__ logits,
        const int*   __restrict__ tgt,
        const int*   __restrict__ parent,
        const int*   __restrict__ counts,
        float* __restrict__ acc,
        int*   __restrict__ done,
        float* __restrict__ out,
        float inv_n,
        int n_pix,
        int nblocks) {
    extern __shared__ float smem[];   // [NCLS][CE_PX]

    const int tid   = threadIdx.x;
    const int wave  = tid >> 6;
    const int pxblk = blockIdx.x * CE_PX;            // block's first pixel
    const int b     = pxblk >> 18;                   // / HWC (block never spans images)
    const int rem   = pxblk & (HWC - 1);
    const float* lp = logits + (size_t)b * NCLS * HWC + rem;

    // ---- stage: 21 classes x 512 px via global_load_lds (16 B/lane) ----
    // LDS dest = wave-uniform base + lane*16; matches smem[c*512 + tid*4].
    {
        const float* g = lp + tid * 4;
        float* l = smem + wave * 256;                // + lane*4 implicit
#pragma unroll
        for (int c = 0; c < NCLS; ++c) {
            __builtin_amdgcn_global_load_lds((gptr_t)(g + (size_t)c * HWC),
                                             (lptr_t)(l + c * CE_PX),
                                             16, 0, 0);
        }
    }
    asm volatile("s_waitcnt vmcnt(0)" ::: "memory");
    __syncthreads();

    // ---- compute: two LDS passes + target select ----
    const int p0 = tid * 4;                          // 16B-aligned
    float local = 0.0f;

    {
        float4 v0 = *reinterpret_cast<const float4*>(smem + p0);
        float m[4] = {v0.x, v0.y, v0.z, v0.w};
#pragma unroll
        for (int c = 1; c < NCLS; ++c) {
            float4 v = *reinterpret_cast<const float4*>(smem + c * CE_PX + p0);
            m[0] = fmaxf(m[0], v.x); m[1] = fmaxf(m[1], v.y);
            m[2] = fmaxf(m[2], v.z); m[3] = fmaxf(m[3], v.w);
        }

        float s[4] = {0.f, 0.f, 0.f, 0.f};
#pragma unroll
        for (int c = 0; c < NCLS; ++c) {
            float4 v = *reinterpret_cast<const float4*>(smem + c * CE_PX + p0);
            s[0] += __expf(v.x - m[0]); s[1] += __expf(v.y - m[1]);
            s[2] += __expf(v.z - m[2]); s[3] += __expf(v.w - m[3]);
        }

        const int base = pxblk + p0;
        int4 t4 = *reinterpret_cast<const int4*>(tgt + base);
        int tj[4] = {t4.x, t4.y, t4.z, t4.w};

        float xt[4];
#pragma unroll
        for (int j = 0; j < 4; ++j)
            xt[j] = smem[tj[j] * CE_PX + p0 + j];    // runtime-indexed LDS read

#pragma unroll
        for (int j = 0; j < 4; ++j) {
            float ce = m[j] + __logf(s[j]) - xt[j];
            float wgt = 1.0f;
            if (tj[j] > 0) {
                int r = parent[base + j];            // fully compressed root
                float size = (float)counts[r];
                if (size < 500.0f)
                    wgt = 3.0f * __logf(size + 1.0f) * INV_LOG_MAXR;
            }
            local += ce * wgt;
        }
    }

    // block reduction: wave64 shuffle, then 2 wave partials through LDS
#pragma unroll
    for (int off = 32; off > 0; off >>= 1)
        local += __shfl_down(local, off, 64);

    __shared__ float red[2];
    int lane = tid & 63;
    if (lane == 0) red[wave] = local;
    __syncthreads();

    if (tid == 0) {
        atomicAdd(acc, red[0] + red[1]);
        __threadfence();
        int t = atomicAdd(done, 1);
        if (t == nblocks - 1) {
            float a = *(volatile float*)acc;
            out[0] = a * inv_n;
        }
    }
}

// ---------------- launch ----------------

extern "C" void kernel_launch(void* const* d_in, const int* in_sizes, int n_in,
                              void* d_out, int out_size, void* d_ws, size_t ws_size,
                              hipStream_t stream) {
    const float* logits = (const float*)d_in[0];
    const int*   tgt    = (const int*)d_in[1];
    float*       out    = (float*)d_out;

    int n_pix = in_sizes[1];               // B*H*W = 4*512*512 = 1048576

    int*   parent = (int*)d_ws;
    int*   counts = parent + n_pix;
    float* acc    = (float*)(counts + n_pix);
    int*   done   = (int*)(acc + 1);

    int blocks4  = (n_pix / 4 + 255) / 256;   // 1024
    int blocksCE = n_pix / CE_PX;             // 2048 (exact: 1M % 512 == 0)

    hipLaunchKernelGGL(init_kernel,  dim3(blocks4), dim3(256), 0, stream, parent, counts, acc, done, n_pix);
    hipLaunchKernelGGL(merge_kernel, dim3(blocks4), dim3(256), 0, stream, tgt, parent, n_pix);
    hipLaunchKernelGGL(count_kernel, dim3(blocks4), dim3(256), 0, stream, tgt, parent, counts, n_pix);
    hipLaunchKernelGGL(ce_weight_kernel, dim3(blocksCE), dim3(CE_BLK),
                       CE_LDS_FLOATS * sizeof(float), stream,
                       logits, tgt, parent, counts, acc, done, out,
                       1.0f / (float)n_pix, n_pix, blocksCE);
}